// Round 1
// baseline (290.298 us; speedup 1.0000x reference)
//
#include <hip/hip_runtime.h>
#include <math.h>

#define NPIX   4096
#define FDIM   64
#define BATCH  2
#define TM     32
#define TN     64
#define SPLIT  4
#define TILES_PER_CHUNK ((NPIX / SPLIT) / TN)   // 16
#define NTHREADS 128
#define APAD   68                                // 64 + 4 pad (keeps 16B align, breaks bank stride)

// ---------------- Kernel 1: rgb -> normalized LAB (both images) ----------------
__device__ __forceinline__ float gamma_expand(float u) {
    return u > 0.04045f ? powf((u + 0.055f) * (1.0f / 1.055f), 2.4f)
                        : u * (1.0f / 12.92f);
}
__device__ __forceinline__ float lab_f(float t) {
    return t > 0.008856f ? cbrtf(t) : 7.787f * t + (16.0f / 116.0f);
}

__global__ void lab_kernel(const float* __restrict__ rgb0,
                           const float* __restrict__ rgb1,
                           float* __restrict__ lab0,
                           float* __restrict__ lab1) {
    int gid = blockIdx.x * blockDim.x + threadIdx.x;      // 0 .. 2*B*N-1
    if (gid >= 2 * BATCH * NPIX) return;
    int img = gid / (BATCH * NPIX);
    int rem = gid - img * (BATCH * NPIX);
    int b = rem / NPIX;
    int n = rem - b * NPIX;
    const float* rgb = img ? rgb1 : rgb0;
    float* lab = img ? lab1 : lab0;

    size_t i0 = (size_t)(b * 3 + 0) * NPIX + n;
    size_t i1 = (size_t)(b * 3 + 1) * NPIX + n;
    size_t i2 = (size_t)(b * 3 + 2) * NPIX + n;

    float r = gamma_expand(rgb[i0] + 0.5f);
    float g = gamma_expand(rgb[i1] + 0.5f);
    float bl = gamma_expand(rgb[i2] + 0.5f);

    float X = (0.412453f * r + 0.357580f * g + 0.180423f * bl) * (1.0f / 0.95047f);
    float Y = (0.212671f * r + 0.715160f * g + 0.072169f * bl);
    float Z = (0.019334f * r + 0.119193f * g + 0.950227f * bl) * (1.0f / 1.08883f);

    float fx = lab_f(X), fy = lab_f(Y), fz = lab_f(Z);
    float L = 116.0f * fy - 16.0f;
    float a = 500.0f * (fx - fy);
    float bb = 200.0f * (fy - fz);

    lab[i0] = (L - 50.0f) * (1.0f / 100.0f);
    lab[i1] = a * (1.0f / 110.0f);
    lab[i2] = bb * (1.0f / 110.0f);
}

// ---------------- Kernel 2: fused corr + online softmax + label accumulate ----------------
// grid = BATCH * SPLIT * (NPIX/TM) blocks, NTHREADS threads.
// Each block: rows [n0, n0+TM) of batch b, m-range [m_base, m_base + NPIX/SPLIT).
// Per-thread 4x4 microtile; private online-softmax state per (row, 4-col-slice).
__global__ __launch_bounds__(NTHREADS) void attn_kernel(
    const float* __restrict__ f0g, const float* __restrict__ f1g,
    const float* __restrict__ lab1ws, float* __restrict__ partials)
{
    __shared__ __align__(16) float Af[TM * APAD];   // [n][f]
    __shared__ __align__(16) float Bf[TN * APAD];   // [m][f]   (reused as epilogue scratch)
    __shared__ __align__(16) float Lt[3 * TN];      // [c][m]

    int bid = blockIdx.x;
    int blocks_per_b = SPLIT * (NPIX / TM);
    int b = bid / blocks_per_b;
    int rem = bid - b * blocks_per_b;
    int chunk = rem / (NPIX / TM);
    int rowblk = rem - chunk * (NPIX / TM);
    int n0 = rowblk * TM;
    int m_base = chunk * (NPIX / SPLIT);

    int tid = threadIdx.x;
    int tx = tid & 15;      // col group (4 cols)
    int ty = tid >> 4;      // row group (4 rows), 0..7
    int r0 = ty * 4;
    int c0 = tx * 4;

    const float inv_t = 1.0f / 0.07f;

    // stage A tile (f0 rows n0..n0+TM), transposed to [n][f], pre-scaled by 1/0.07
    #pragma unroll
    for (int i = 0; i < (TM * FDIM) / NTHREADS; ++i) {   // 16 iters
        int idx = i * NTHREADS + tid;
        int f = idx >> 5;        // 32 n's per f
        int n = idx & 31;
        Af[n * APAD + f] = inv_t * f0g[(size_t)(b * FDIM + f) * NPIX + n0 + n];
    }

    float m_st[4], sum_st[4], s0_st[4], s1_st[4], s2_st[4];
    #pragma unroll
    for (int r = 0; r < 4; ++r) {
        m_st[r] = -INFINITY; sum_st[r] = 0.0f;
        s0_st[r] = 0.0f; s1_st[r] = 0.0f; s2_st[r] = 0.0f;
    }

    for (int t = 0; t < TILES_PER_CHUNK; ++t) {
        int m0 = m_base + t * TN;
        __syncthreads();   // protect previous tile reads (and A staging on t=0)
        // stage B tile transposed to [m][f]
        #pragma unroll
        for (int i = 0; i < (TN * FDIM) / NTHREADS; ++i) {  // 32 iters
            int idx = i * NTHREADS + tid;
            int f = idx >> 6;
            int m = idx & 63;
            Bf[m * APAD + f] = f1g[(size_t)(b * FDIM + f) * NPIX + m0 + m];
        }
        // stage lab1 tile [3][TN]
        for (int i = tid; i < 3 * TN; i += NTHREADS) {
            int c = i >> 6, m = i & 63;
            Lt[c * TN + m] = lab1ws[(size_t)(b * 3 + c) * NPIX + m0 + m];
        }
        __syncthreads();

        float acc[4][4];
        #pragma unroll
        for (int r = 0; r < 4; ++r)
            #pragma unroll
            for (int c = 0; c < 4; ++c) acc[r][c] = 0.0f;

        #pragma unroll
        for (int f = 0; f < FDIM; f += 4) {
            float4 av[4], bv[4];
            #pragma unroll
            for (int r = 0; r < 4; ++r)
                av[r] = *(const float4*)&Af[(r0 + r) * APAD + f];
            #pragma unroll
            for (int c = 0; c < 4; ++c)
                bv[c] = *(const float4*)&Bf[(c0 + c) * APAD + f];
            #pragma unroll
            for (int r = 0; r < 4; ++r)
                #pragma unroll
                for (int c = 0; c < 4; ++c) {
                    acc[r][c] += av[r].x * bv[c].x;
                    acc[r][c] += av[r].y * bv[c].y;
                    acc[r][c] += av[r].z * bv[c].z;
                    acc[r][c] += av[r].w * bv[c].w;
                }
        }

        // per-thread online softmax update over this thread's 4-col slice
        float4 lb0 = *(const float4*)&Lt[0 * TN + c0];
        float4 lb1v = *(const float4*)&Lt[1 * TN + c0];
        float4 lb2 = *(const float4*)&Lt[2 * TN + c0];
        #pragma unroll
        for (int r = 0; r < 4; ++r) {
            float tmax = fmaxf(fmaxf(acc[r][0], acc[r][1]), fmaxf(acc[r][2], acc[r][3]));
            float nm = fmaxf(m_st[r], tmax);
            float sc = __expf(m_st[r] - nm);
            float p0 = __expf(acc[r][0] - nm);
            float p1 = __expf(acc[r][1] - nm);
            float p2 = __expf(acc[r][2] - nm);
            float p3 = __expf(acc[r][3] - nm);
            sum_st[r] = sum_st[r] * sc + ((p0 + p1) + (p2 + p3));
            s0_st[r] = s0_st[r] * sc + (p0 * lb0.x + p1 * lb0.y + p2 * lb0.z + p3 * lb0.w);
            s1_st[r] = s1_st[r] * sc + (p0 * lb1v.x + p1 * lb1v.y + p2 * lb1v.z + p3 * lb1v.w);
            s2_st[r] = s2_st[r] * sc + (p0 * lb2.x + p1 * lb2.y + p2 * lb2.z + p3 * lb2.w);
            m_st[r] = nm;
        }
    }

    // epilogue: merge the 16 col-group partials per row
    __syncthreads();
    float* scratch = Bf;   // 64*68 = 4352 floats >= 32*16*5 = 2560
    #pragma unroll
    for (int r = 0; r < 4; ++r) {
        int row = r0 + r;
        int base = (row * 16 + tx) * 5;
        scratch[base + 0] = m_st[r];
        scratch[base + 1] = sum_st[r];
        scratch[base + 2] = s0_st[r];
        scratch[base + 3] = s1_st[r];
        scratch[base + 4] = s2_st[r];
    }
    __syncthreads();
    if (tid < TM) {
        int row = tid;
        float M = -INFINITY;
        for (int g = 0; g < 16; ++g) M = fmaxf(M, scratch[(row * 16 + g) * 5]);
        float S = 0.0f, A0 = 0.0f, A1 = 0.0f, A2 = 0.0f;
        for (int g = 0; g < 16; ++g) {
            const float* p = &scratch[(row * 16 + g) * 5];
            float w = __expf(p[0] - M);
            S  += p[1] * w;
            A0 += p[2] * w;
            A1 += p[3] * w;
            A2 += p[4] * w;
        }
        size_t pb = (size_t)(b * SPLIT + chunk) * 5 * NPIX + (n0 + row);
        partials[pb + 0 * NPIX] = M;
        partials[pb + 1 * NPIX] = S;
        partials[pb + 2 * NPIX] = A0;
        partials[pb + 3 * NPIX] = A1;
        partials[pb + 4 * NPIX] = A2;
    }
}

// ---------------- Kernel 3: merge chunks, diff, L1+Huber, reduce ----------------
__global__ void loss_kernel(const float* __restrict__ partials,
                            const float* __restrict__ lab0ws,
                            float* __restrict__ out)
{
    int gid = blockIdx.x * blockDim.x + threadIdx.x;   // 0..8191
    int b = gid >> 12;
    int n = gid & (NPIX - 1);

    float mc[SPLIT];
    float M = -INFINITY;
    #pragma unroll
    for (int ch = 0; ch < SPLIT; ++ch) {
        mc[ch] = partials[((size_t)(b * SPLIT + ch) * 5 + 0) * NPIX + n];
        M = fmaxf(M, mc[ch]);
    }
    float S = 0.0f, A0 = 0.0f, A1 = 0.0f, A2 = 0.0f;
    #pragma unroll
    for (int ch = 0; ch < SPLIT; ++ch) {
        size_t base = (size_t)(b * SPLIT + ch) * 5 * NPIX + n;
        float w = __expf(mc[ch] - M);
        S  += partials[base + 1 * NPIX] * w;
        A0 += partials[base + 2 * NPIX] * w;
        A1 += partials[base + 3 * NPIX] * w;
        A2 += partials[base + 4 * NPIX] * w;
    }
    float inv_s = 1.0f / S;
    float d0 = A0 * inv_s - lab0ws[(size_t)(b * 3 + 0) * NPIX + n];
    float d1 = A1 * inv_s - lab0ws[(size_t)(b * 3 + 1) * NPIX + n];
    float d2 = A2 * inv_s - lab0ws[(size_t)(b * 3 + 2) * NPIX + n];

    float val = 0.0f;
    #pragma unroll
    for (int c = 0; c < 3; ++c) {
        float d = (c == 0) ? d0 : (c == 1) ? d1 : d2;
        float ad = fabsf(d);
        float hub = (ad < 1.0f) ? 0.5f * ad * ad : ad - 0.5f;
        val += ad + hub;
    }

    // wave reduce (64 lanes)
    #pragma unroll
    for (int off = 32; off > 0; off >>= 1)
        val += __shfl_down(val, off);

    __shared__ float wsum[4];
    int lane = threadIdx.x & 63;
    int wave = threadIdx.x >> 6;
    if (lane == 0) wsum[wave] = val;
    __syncthreads();
    if (threadIdx.x == 0) {
        float s = wsum[0] + wsum[1] + wsum[2] + wsum[3];
        atomicAdd(out, s * (1.0f / 8192.0f));
    }
}

// ---------------- launcher ----------------
extern "C" void kernel_launch(void* const* d_in, const int* in_sizes, int n_in,
                              void* d_out, int out_size, void* d_ws, size_t ws_size,
                              hipStream_t stream) {
    const float* rgb0  = (const float*)d_in[0];
    const float* rgb1  = (const float*)d_in[1];
    const float* feat0 = (const float*)d_in[2];
    const float* feat1 = (const float*)d_in[3];
    float* out = (float*)d_out;
    float* ws  = (float*)d_ws;

    float* lab0 = ws;                       // B*3*N = 24576 floats
    float* lab1 = ws + 24576;               // 24576 floats
    float* partials = ws + 49152;           // B*SPLIT*5*N = 163840 floats

    hipMemsetAsync(d_out, 0, sizeof(float), stream);

    lab_kernel<<<(2 * BATCH * NPIX + 255) / 256, 256, 0, stream>>>(rgb0, rgb1, lab0, lab1);

    int attn_grid = BATCH * SPLIT * (NPIX / TM);   // 1024
    attn_kernel<<<attn_grid, NTHREADS, 0, stream>>>(feat0, feat1, lab1, partials);

    loss_kernel<<<(BATCH * NPIX) / 256, 256, 0, stream>>>(partials, lab0, out);
}

// Round 2
// 139.694 us; speedup vs baseline: 2.0781x; 2.0781x over previous
//
#include <hip/hip_runtime.h>
#include <math.h>

#define NPIX   4096
#define FDIM   64
#define BATCH  2
#define TM     32
#define TN     64
#define SPLIT  4
#define TILES_PER_CHUNK ((NPIX / SPLIT) / TN)   // 16
#define NTHREADS 128

// ---------------- Kernel 1: rgb -> normalized LAB (both images) ----------------
__device__ __forceinline__ float gamma_expand(float u) {
    return u > 0.04045f ? powf((u + 0.055f) * (1.0f / 1.055f), 2.4f)
                        : u * (1.0f / 12.92f);
}
__device__ __forceinline__ float lab_f(float t) {
    return t > 0.008856f ? cbrtf(t) : 7.787f * t + (16.0f / 116.0f);
}

__global__ void lab_kernel(const float* __restrict__ rgb0,
                           const float* __restrict__ rgb1,
                           float* __restrict__ lab0,
                           float* __restrict__ lab1) {
    int gid = blockIdx.x * blockDim.x + threadIdx.x;      // 0 .. 2*B*N-1
    if (gid >= 2 * BATCH * NPIX) return;
    int img = gid / (BATCH * NPIX);
    int rem = gid - img * (BATCH * NPIX);
    int b = rem / NPIX;
    int n = rem - b * NPIX;
    const float* rgb = img ? rgb1 : rgb0;
    float* lab = img ? lab1 : lab0;

    size_t i0 = (size_t)(b * 3 + 0) * NPIX + n;
    size_t i1 = (size_t)(b * 3 + 1) * NPIX + n;
    size_t i2 = (size_t)(b * 3 + 2) * NPIX + n;

    float r = gamma_expand(rgb[i0] + 0.5f);
    float g = gamma_expand(rgb[i1] + 0.5f);
    float bl = gamma_expand(rgb[i2] + 0.5f);

    float X = (0.412453f * r + 0.357580f * g + 0.180423f * bl) * (1.0f / 0.95047f);
    float Y = (0.212671f * r + 0.715160f * g + 0.072169f * bl);
    float Z = (0.019334f * r + 0.119193f * g + 0.950227f * bl) * (1.0f / 1.08883f);

    float fx = lab_f(X), fy = lab_f(Y), fz = lab_f(Z);
    float L = 116.0f * fy - 16.0f;
    float a = 500.0f * (fx - fy);
    float bb = 200.0f * (fy - fz);

    lab[i0] = (L - 50.0f) * (1.0f / 100.0f);
    lab[i1] = a * (1.0f / 110.0f);
    lab[i2] = bb * (1.0f / 110.0f);
}

// ---------------- Kernel 2: fused corr + online softmax + label accumulate ----------------
// f-major LDS tiles: Af[f][TM], Bf[f][TN] — conflict-free float4 reads, and
// B staging is a direct f-major copy (no transpose). Softmax in log2 space:
// scale A by log2(e)/0.07 at staging; all exps are native v_exp_f32 (exp2).
__global__ __launch_bounds__(NTHREADS) void attn_kernel(
    const float* __restrict__ f0g, const float* __restrict__ f1g,
    const float* __restrict__ lab1ws, float* __restrict__ partials)
{
    __shared__ __align__(16) float Af[FDIM * TM];   // [f][n]  2048 floats
    __shared__ __align__(16) float Bf[FDIM * TN];   // [f][m]  4096 floats (epilogue scratch too)
    __shared__ __align__(16) float Lt[3 * TN];      // [c][m]

    int bid = blockIdx.x;
    int blocks_per_b = SPLIT * (NPIX / TM);
    int b = bid / blocks_per_b;
    int rem = bid - b * blocks_per_b;
    int chunk = rem / (NPIX / TM);
    int rowblk = rem - chunk * (NPIX / TM);
    int n0 = rowblk * TM;
    int m_base = chunk * (NPIX / SPLIT);

    int tid = threadIdx.x;
    int tx = tid & 15;      // col group (4 cols)
    int ty = tid >> 4;      // row group (4 rows), 0..7
    int r0 = ty * 4;
    int c0 = tx * 4;

    const float inv_t = 1.442695040888963f / 0.07f;   // log2(e)/0.07 -> logits in log2 space

    // stage A tile f-major [f][TM], pre-scaled
    #pragma unroll
    for (int i = 0; i < 4; ++i) {
        int idx = i * NTHREADS + tid;          // 0..511 float4s
        int f = idx >> 3;                       // 8 float4 per f-row
        int n4 = idx & 7;
        float4 v = *(const float4*)&f0g[(size_t)(b * FDIM + f) * NPIX + n0 + n4 * 4];
        v.x *= inv_t; v.y *= inv_t; v.z *= inv_t; v.w *= inv_t;
        *(float4*)&Af[f * TM + n4 * 4] = v;
    }

    float m_st[4], sum_st[4], s0_st[4], s1_st[4], s2_st[4];
    #pragma unroll
    for (int r = 0; r < 4; ++r) {
        m_st[r] = -INFINITY; sum_st[r] = 0.0f;
        s0_st[r] = 0.0f; s1_st[r] = 0.0f; s2_st[r] = 0.0f;
    }

    for (int t = 0; t < TILES_PER_CHUNK; ++t) {
        int m0 = m_base + t * TN;
        __syncthreads();   // protect previous tile reads (covers A staging at t=0)
        // stage B tile f-major [f][TN] — direct copy, float4
        #pragma unroll
        for (int i = 0; i < 8; ++i) {
            int idx = i * NTHREADS + tid;      // 0..1023 float4s
            int f = idx >> 4;                   // 16 float4 per f-row
            int m4 = idx & 15;
            *(float4*)&Bf[f * TN + m4 * 4] =
                *(const float4*)&f1g[(size_t)(b * FDIM + f) * NPIX + m0 + m4 * 4];
        }
        if (tid < 48) {
            int c = tid >> 4, m4 = tid & 15;
            *(float4*)&Lt[c * TN + m4 * 4] =
                *(const float4*)&lab1ws[(size_t)(b * 3 + c) * NPIX + m0 + m4 * 4];
        }
        __syncthreads();

        float acc[4][4];
        #pragma unroll
        for (int r = 0; r < 4; ++r)
            #pragma unroll
            for (int c = 0; c < 4; ++c) acc[r][c] = 0.0f;

        #pragma unroll 8
        for (int f = 0; f < FDIM; ++f) {
            float4 av = *(const float4*)&Af[f * TM + r0];
            float4 bv = *(const float4*)&Bf[f * TN + c0];
            acc[0][0] += av.x * bv.x; acc[0][1] += av.x * bv.y;
            acc[0][2] += av.x * bv.z; acc[0][3] += av.x * bv.w;
            acc[1][0] += av.y * bv.x; acc[1][1] += av.y * bv.y;
            acc[1][2] += av.y * bv.z; acc[1][3] += av.y * bv.w;
            acc[2][0] += av.z * bv.x; acc[2][1] += av.z * bv.y;
            acc[2][2] += av.z * bv.z; acc[2][3] += av.z * bv.w;
            acc[3][0] += av.w * bv.x; acc[3][1] += av.w * bv.y;
            acc[3][2] += av.w * bv.z; acc[3][3] += av.w * bv.w;
        }

        // per-thread online softmax (log2 space) over this thread's 4-col slice
        float4 lb0 = *(const float4*)&Lt[0 * TN + c0];
        float4 lb1v = *(const float4*)&Lt[1 * TN + c0];
        float4 lb2 = *(const float4*)&Lt[2 * TN + c0];
        #pragma unroll
        for (int r = 0; r < 4; ++r) {
            float tmax = fmaxf(fmaxf(acc[r][0], acc[r][1]), fmaxf(acc[r][2], acc[r][3]));
            float nm = fmaxf(m_st[r], tmax);
            float sc = __builtin_amdgcn_exp2f(m_st[r] - nm);
            float p0 = __builtin_amdgcn_exp2f(acc[r][0] - nm);
            float p1 = __builtin_amdgcn_exp2f(acc[r][1] - nm);
            float p2 = __builtin_amdgcn_exp2f(acc[r][2] - nm);
            float p3 = __builtin_amdgcn_exp2f(acc[r][3] - nm);
            sum_st[r] = sum_st[r] * sc + ((p0 + p1) + (p2 + p3));
            s0_st[r] = s0_st[r] * sc + (p0 * lb0.x + p1 * lb0.y + p2 * lb0.z + p3 * lb0.w);
            s1_st[r] = s1_st[r] * sc + (p0 * lb1v.x + p1 * lb1v.y + p2 * lb1v.z + p3 * lb1v.w);
            s2_st[r] = s2_st[r] * sc + (p0 * lb2.x + p1 * lb2.y + p2 * lb2.z + p3 * lb2.w);
            m_st[r] = nm;
        }
    }

    // epilogue: merge the 16 col-group partials per row (still log2-space maxes)
    __syncthreads();
    float* scratch = Bf;   // 4096 floats >= 32*16*5 = 2560
    #pragma unroll
    for (int r = 0; r < 4; ++r) {
        int row = r0 + r;
        int base = (row * 16 + tx) * 5;
        scratch[base + 0] = m_st[r];
        scratch[base + 1] = sum_st[r];
        scratch[base + 2] = s0_st[r];
        scratch[base + 3] = s1_st[r];
        scratch[base + 4] = s2_st[r];
    }
    __syncthreads();
    if (tid < TM) {
        int row = tid;
        float M = -INFINITY;
        for (int g = 0; g < 16; ++g) M = fmaxf(M, scratch[(row * 16 + g) * 5]);
        float S = 0.0f, A0 = 0.0f, A1 = 0.0f, A2 = 0.0f;
        for (int g = 0; g < 16; ++g) {
            const float* p = &scratch[(row * 16 + g) * 5];
            float w = __builtin_amdgcn_exp2f(p[0] - M);
            S  += p[1] * w;
            A0 += p[2] * w;
            A1 += p[3] * w;
            A2 += p[4] * w;
        }
        size_t pb = (size_t)(b * SPLIT + chunk) * 5 * NPIX + (n0 + row);
        partials[pb + 0 * NPIX] = M;
        partials[pb + 1 * NPIX] = S;
        partials[pb + 2 * NPIX] = A0;
        partials[pb + 3 * NPIX] = A1;
        partials[pb + 4 * NPIX] = A2;
    }
}

// ---------------- Kernel 3: merge chunks, diff, L1+Huber, reduce ----------------
__global__ void loss_kernel(const float* __restrict__ partials,
                            const float* __restrict__ lab0ws,
                            float* __restrict__ out)
{
    int gid = blockIdx.x * blockDim.x + threadIdx.x;   // 0..8191
    int b = gid >> 12;
    int n = gid & (NPIX - 1);

    float mc[SPLIT];
    float M = -INFINITY;
    #pragma unroll
    for (int ch = 0; ch < SPLIT; ++ch) {
        mc[ch] = partials[((size_t)(b * SPLIT + ch) * 5 + 0) * NPIX + n];
        M = fmaxf(M, mc[ch]);
    }
    float S = 0.0f, A0 = 0.0f, A1 = 0.0f, A2 = 0.0f;
    #pragma unroll
    for (int ch = 0; ch < SPLIT; ++ch) {
        size_t base = (size_t)(b * SPLIT + ch) * 5 * NPIX + n;
        float w = __builtin_amdgcn_exp2f(mc[ch] - M);
        S  += partials[base + 1 * NPIX] * w;
        A0 += partials[base + 2 * NPIX] * w;
        A1 += partials[base + 3 * NPIX] * w;
        A2 += partials[base + 4 * NPIX] * w;
    }
    float inv_s = 1.0f / S;
    float d0 = A0 * inv_s - lab0ws[(size_t)(b * 3 + 0) * NPIX + n];
    float d1 = A1 * inv_s - lab0ws[(size_t)(b * 3 + 1) * NPIX + n];
    float d2 = A2 * inv_s - lab0ws[(size_t)(b * 3 + 2) * NPIX + n];

    float val = 0.0f;
    #pragma unroll
    for (int c = 0; c < 3; ++c) {
        float d = (c == 0) ? d0 : (c == 1) ? d1 : d2;
        float ad = fabsf(d);
        float hub = (ad < 1.0f) ? 0.5f * ad * ad : ad - 0.5f;
        val += ad + hub;
    }

    // wave reduce (64 lanes)
    #pragma unroll
    for (int off = 32; off > 0; off >>= 1)
        val += __shfl_down(val, off);

    __shared__ float wsum[4];
    int lane = threadIdx.x & 63;
    int wave = threadIdx.x >> 6;
    if (lane == 0) wsum[wave] = val;
    __syncthreads();
    if (threadIdx.x == 0) {
        float s = wsum[0] + wsum[1] + wsum[2] + wsum[3];
        atomicAdd(out, s * (1.0f / 8192.0f));
    }
}

// ---------------- launcher ----------------
extern "C" void kernel_launch(void* const* d_in, const int* in_sizes, int n_in,
                              void* d_out, int out_size, void* d_ws, size_t ws_size,
                              hipStream_t stream) {
    const float* rgb0  = (const float*)d_in[0];
    const float* rgb1  = (const float*)d_in[1];
    const float* feat0 = (const float*)d_in[2];
    const float* feat1 = (const float*)d_in[3];
    float* out = (float*)d_out;
    float* ws  = (float*)d_ws;

    float* lab0 = ws;                       // B*3*N = 24576 floats
    float* lab1 = ws + 24576;               // 24576 floats
    float* partials = ws + 49152;           // B*SPLIT*5*N = 163840 floats

    hipMemsetAsync(d_out, 0, sizeof(float), stream);

    lab_kernel<<<(2 * BATCH * NPIX + 255) / 256, 256, 0, stream>>>(rgb0, rgb1, lab0, lab1);

    int attn_grid = BATCH * SPLIT * (NPIX / TM);   // 1024
    attn_kernel<<<attn_grid, NTHREADS, 0, stream>>>(feat0, feat1, lab1, partials);

    loss_kernel<<<(BATCH * NPIX) / 256, 256, 0, stream>>>(partials, lab0, out);
}

// Round 3
// 89.122 us; speedup vs baseline: 3.2573x; 1.5674x over previous
//
#include <hip/hip_runtime.h>
#include <math.h>

#define NPIX   4096
#define FDIM   64
#define BATCH  2
#define SPLIT  8
#define CHUNK  (NPIX / SPLIT)      // 512
#define NGROUP (CHUNK / 64)        // 8 groups of 64 cols

typedef __attribute__((ext_vector_type(8))) short short8;
typedef __attribute__((ext_vector_type(4))) float floatx4;

__device__ __forceinline__ float exp2f_(float x) { return __builtin_amdgcn_exp2f(x); }

// round-to-nearest-even fp32 -> bf16
__device__ __forceinline__ short f2bf(float x) {
    union { float f; unsigned u; } c; c.f = x;
    unsigned r = (c.u + 0x7FFFu + ((c.u >> 16) & 1u)) >> 16;
    return (short)r;
}

// ---------------- LAB helpers ----------------
__device__ __forceinline__ float gamma_expand(float u) {
    return u > 0.04045f ? powf((u + 0.055f) * (1.0f / 1.055f), 2.4f)
                        : u * (1.0f / 12.92f);
}
__device__ __forceinline__ float lab_f(float t) {
    return t > 0.008856f ? cbrtf(t) : 7.787f * t + (16.0f / 116.0f);
}

// ---------------- Kernel 1: prep = feat transpose->bf16 (blocks 0..255) + LAB (blocks 256..319) ----
// f0t/f1t: [b][n][f] bf16; f0t pre-scaled by log2(e)/0.07 (logits come out in log2 space).
__global__ __launch_bounds__(256) void prep_kernel(
    const float* __restrict__ rgb0, const float* __restrict__ rgb1,
    const float* __restrict__ feat0, const float* __restrict__ feat1,
    float* __restrict__ lab0, float* __restrict__ lab1,
    short* __restrict__ f0t, short* __restrict__ f1t)
{
    int bid = blockIdx.x;
    int tid = threadIdx.x;

    if (bid < 256) {
        // transpose+convert one 64-n tile of one tensor/batch
        __shared__ short Tsm[64 * 72];
        int pair = bid >> 6;            // 0..3
        int tensor = pair >> 1;         // 0: f0, 1: f1
        int bb = pair & 1;
        int n0 = (bid & 63) * 64;
        const float* src = (tensor ? feat1 : feat0) + (size_t)bb * FDIM * NPIX;
        short* dst = (tensor ? f1t : f0t) + (size_t)bb * NPIX * FDIM;
        float scale = tensor ? 1.0f : (1.442695040888963f / 0.07f);

        int f = tid >> 2;
        int slot = tid & 3;
        #pragma unroll
        for (int i = 0; i < 4; ++i) {
            int col4 = slot * 4 + i;       // 0..15
            int noff = col4 * 4;
            float4 v = *(const float4*)&src[(size_t)f * NPIX + n0 + noff];
            Tsm[(noff + 0) * 72 + f] = f2bf(v.x * scale);
            Tsm[(noff + 1) * 72 + f] = f2bf(v.y * scale);
            Tsm[(noff + 2) * 72 + f] = f2bf(v.z * scale);
            Tsm[(noff + 3) * 72 + f] = f2bf(v.w * scale);
        }
        __syncthreads();
        #pragma unroll
        for (int i = 0; i < 2; ++i) {
            int idx = i * 256 + tid;       // 0..511
            int row = idx >> 3, ch = idx & 7;
            *(short8*)&dst[(size_t)(n0 + row) * FDIM + ch * 8] =
                *(const short8*)&Tsm[row * 72 + ch * 8];
        }
        return;
    }

    // LAB branch
    int gid = (bid - 256) * 256 + tid;     // 0 .. 16383
    int img = gid / (BATCH * NPIX);
    int rem = gid - img * (BATCH * NPIX);
    int b = rem / NPIX;
    int n = rem - b * NPIX;
    const float* rgb = img ? rgb1 : rgb0;
    float* lab = img ? lab1 : lab0;

    size_t i0 = (size_t)(b * 3 + 0) * NPIX + n;
    size_t i1 = (size_t)(b * 3 + 1) * NPIX + n;
    size_t i2 = (size_t)(b * 3 + 2) * NPIX + n;

    float r = gamma_expand(rgb[i0] + 0.5f);
    float g = gamma_expand(rgb[i1] + 0.5f);
    float bl = gamma_expand(rgb[i2] + 0.5f);

    float X = (0.412453f * r + 0.357580f * g + 0.180423f * bl) * (1.0f / 0.95047f);
    float Y = (0.212671f * r + 0.715160f * g + 0.072169f * bl);
    float Z = (0.019334f * r + 0.119193f * g + 0.950227f * bl) * (1.0f / 1.08883f);

    float fx = lab_f(X), fy = lab_f(Y), fz = lab_f(Z);
    float L = 116.0f * fy - 16.0f;
    float a = 500.0f * (fx - fy);
    float bb2 = 200.0f * (fy - fz);

    lab[i0] = (L - 50.0f) * (1.0f / 100.0f);
    lab[i1] = a * (1.0f / 110.0f);
    lab[i2] = bb2 * (1.0f / 110.0f);
}

// ---------------- Kernel 2: MFMA attn + online softmax + label accumulate ----------------
// 4 waves/block; wave w owns rows n0+w*16 .. +15; m-chunk of 512 cols in 8 groups of 64.
// mfma_f32_16x16x32_bf16; A hoisted from global f0t; B staged in LDS [m][72] bf16.
// Per-lane online state per (row=q*4+r, col-class c=lane&15); quad butterfly merge at end.
__global__ __launch_bounds__(256, 4) void attn_kernel(
    const short* __restrict__ f0t, const short* __restrict__ f1t,
    const float* __restrict__ lab1ws, float* __restrict__ partials)
{
    __shared__ short Bsm[64 * 72];
    __shared__ float Lt[3 * 64];

    int bid = blockIdx.x;
    int rowblk = bid & 63;
    int chunk = (bid >> 6) & 7;
    int b = bid >> 9;
    int n0 = rowblk * 64;
    int m_base = chunk * CHUNK;

    int tid = threadIdx.x;
    int w = tid >> 6;
    int l = tid & 63;
    int c = l & 15;
    int q = l >> 4;

    // hoisted A fragments: A[m = c][k = q*8 + j], k-halves 0..31 / 32..63
    const short8* aptr = (const short8*)(f0t +
        ((size_t)b * NPIX + n0 + w * 16 + c) * FDIM + q * 8);
    short8 a0 = aptr[0];
    short8 a1 = aptr[4];          // +32 shorts

    float m_st[4], sum_st[4], s0_st[4], s1_st[4], s2_st[4];
    #pragma unroll
    for (int r = 0; r < 4; ++r) {
        m_st[r] = -INFINITY; sum_st[r] = 0.0f;
        s0_st[r] = 0.0f; s1_st[r] = 0.0f; s2_st[r] = 0.0f;
    }

    for (int g = 0; g < NGROUP; ++g) {
        int m0 = m_base + g * 64;
        __syncthreads();
        // stage B: 64 rows (cols m0..m0+63) x 64 k, bf16, pad 72
        #pragma unroll
        for (int i = 0; i < 2; ++i) {
            int idx = i * 256 + tid;
            int row = idx >> 3, ch = idx & 7;
            *(short8*)&Bsm[row * 72 + ch * 8] =
                *(const short8*)&f1t[((size_t)b * NPIX + m0 + row) * FDIM + ch * 8];
        }
        if (tid < 48) {
            int cc = tid >> 4, m4 = tid & 15;
            *(float4*)&Lt[cc * 64 + m4 * 4] =
                *(const float4*)&lab1ws[(size_t)(b * 3 + cc) * NPIX + m0 + m4 * 4];
        }
        __syncthreads();

        floatx4 acc[4];
        #pragma unroll
        for (int t = 0; t < 4; ++t) acc[t] = (floatx4)(0.0f);

        #pragma unroll
        for (int t = 0; t < 4; ++t) {
            const short8* bp = (const short8*)&Bsm[(t * 16 + c) * 72 + q * 8];
            short8 b0 = bp[0];
            short8 b1 = bp[4];    // +32 shorts
            acc[t] = __builtin_amdgcn_mfma_f32_16x16x32_bf16(a0, b0, acc[t], 0, 0, 0);
            acc[t] = __builtin_amdgcn_mfma_f32_16x16x32_bf16(a1, b1, acc[t], 0, 0, 0);
        }

        float lA[4], lB[4], lC[4];
        #pragma unroll
        for (int t = 0; t < 4; ++t) {
            lA[t] = Lt[0 * 64 + t * 16 + c];
            lB[t] = Lt[1 * 64 + t * 16 + c];
            lC[t] = Lt[2 * 64 + t * 16 + c];
        }

        #pragma unroll
        for (int r = 0; r < 4; ++r) {
            float L0 = acc[0][r], L1 = acc[1][r], L2 = acc[2][r], L3 = acc[3][r];
            float tmax = fmaxf(fmaxf(L0, L1), fmaxf(L2, L3));
            float nm = fmaxf(m_st[r], tmax);
            float sc = exp2f_(m_st[r] - nm);
            float p0 = exp2f_(L0 - nm);
            float p1 = exp2f_(L1 - nm);
            float p2 = exp2f_(L2 - nm);
            float p3 = exp2f_(L3 - nm);
            sum_st[r] = sum_st[r] * sc + ((p0 + p1) + (p2 + p3));
            s0_st[r] = s0_st[r] * sc + ((p0 * lA[0] + p1 * lA[1]) + (p2 * lA[2] + p3 * lA[3]));
            s1_st[r] = s1_st[r] * sc + ((p0 * lB[0] + p1 * lB[1]) + (p2 * lB[2] + p3 * lB[3]));
            s2_st[r] = s2_st[r] * sc + ((p0 * lC[0] + p1 * lC[1]) + (p2 * lC[2] + p3 * lC[3]));
            m_st[r] = nm;
        }
    }

    // butterfly merge across the 16 col-class lanes of each quad
    #pragma unroll
    for (int mask = 1; mask <= 8; mask <<= 1) {
        #pragma unroll
        for (int r = 0; r < 4; ++r) {
            float om = __shfl_xor(m_st[r], mask, 64);
            float os = __shfl_xor(sum_st[r], mask, 64);
            float o0 = __shfl_xor(s0_st[r], mask, 64);
            float o1 = __shfl_xor(s1_st[r], mask, 64);
            float o2 = __shfl_xor(s2_st[r], mask, 64);
            float nm = fmaxf(m_st[r], om);
            float w1 = exp2f_(m_st[r] - nm);
            float w2 = exp2f_(om - nm);
            sum_st[r] = sum_st[r] * w1 + os * w2;
            s0_st[r] = s0_st[r] * w1 + o0 * w2;
            s1_st[r] = s1_st[r] * w1 + o1 * w2;
            s2_st[r] = s2_st[r] * w1 + o2 * w2;
            m_st[r] = nm;
        }
    }

    if (c == 0) {
        #pragma unroll
        for (int r = 0; r < 4; ++r) {
            int row_g = n0 + w * 16 + q * 4 + r;
            size_t base = (size_t)(b * SPLIT + chunk) * 5 * NPIX + row_g;
            partials[base + 0 * NPIX] = m_st[r];
            partials[base + 1 * NPIX] = sum_st[r];
            partials[base + 2 * NPIX] = s0_st[r];
            partials[base + 3 * NPIX] = s1_st[r];
            partials[base + 4 * NPIX] = s2_st[r];
        }
    }
}

// ---------------- Kernel 3: merge chunks, diff, L1+Huber, reduce ----------------
__global__ void loss_kernel(const float* __restrict__ partials,
                            const float* __restrict__ lab0ws,
                            float* __restrict__ out)
{
    int gid = blockIdx.x * blockDim.x + threadIdx.x;   // 0..8191
    int b = gid >> 12;
    int n = gid & (NPIX - 1);

    float mc[SPLIT];
    float M = -INFINITY;
    #pragma unroll
    for (int ch = 0; ch < SPLIT; ++ch) {
        mc[ch] = partials[((size_t)(b * SPLIT + ch) * 5 + 0) * NPIX + n];
        M = fmaxf(M, mc[ch]);
    }
    float S = 0.0f, A0 = 0.0f, A1 = 0.0f, A2 = 0.0f;
    #pragma unroll
    for (int ch = 0; ch < SPLIT; ++ch) {
        size_t base = (size_t)(b * SPLIT + ch) * 5 * NPIX + n;
        float w = exp2f_(mc[ch] - M);
        S  += partials[base + 1 * NPIX] * w;
        A0 += partials[base + 2 * NPIX] * w;
        A1 += partials[base + 3 * NPIX] * w;
        A2 += partials[base + 4 * NPIX] * w;
    }
    float inv_s = 1.0f / S;
    float d0 = A0 * inv_s - lab0ws[(size_t)(b * 3 + 0) * NPIX + n];
    float d1 = A1 * inv_s - lab0ws[(size_t)(b * 3 + 1) * NPIX + n];
    float d2 = A2 * inv_s - lab0ws[(size_t)(b * 3 + 2) * NPIX + n];

    float val = 0.0f;
    #pragma unroll
    for (int cc = 0; cc < 3; ++cc) {
        float d = (cc == 0) ? d0 : (cc == 1) ? d1 : d2;
        float ad = fabsf(d);
        float hub = (ad < 1.0f) ? 0.5f * ad * ad : ad - 0.5f;
        val += ad + hub;
    }

    #pragma unroll
    for (int off = 32; off > 0; off >>= 1)
        val += __shfl_down(val, off);

    __shared__ float wsum[4];
    int lane = threadIdx.x & 63;
    int wave = threadIdx.x >> 6;
    if (lane == 0) wsum[wave] = val;
    __syncthreads();
    if (threadIdx.x == 0) {
        float s = wsum[0] + wsum[1] + wsum[2] + wsum[3];
        atomicAdd(out, s * (1.0f / 8192.0f));
    }
}

// ---------------- launcher ----------------
extern "C" void kernel_launch(void* const* d_in, const int* in_sizes, int n_in,
                              void* d_out, int out_size, void* d_ws, size_t ws_size,
                              hipStream_t stream) {
    const float* rgb0  = (const float*)d_in[0];
    const float* rgb1  = (const float*)d_in[1];
    const float* feat0 = (const float*)d_in[2];
    const float* feat1 = (const float*)d_in[3];
    float* out = (float*)d_out;
    float* ws  = (float*)d_ws;

    float* lab0 = ws;                         // 24576 floats
    float* lab1 = ws + 24576;                 // 24576 floats
    float* partials = ws + 49152;             // 2*8*5*4096 = 327680 floats
    short* f0t = (short*)(ws + 376832);       // 2*4096*64 shorts = 1 MB
    short* f1t = f0t + (size_t)BATCH * NPIX * FDIM;

    hipMemsetAsync(d_out, 0, sizeof(float), stream);

    prep_kernel<<<320, 256, 0, stream>>>(rgb0, rgb1, feat0, feat1, lab0, lab1, f0t, f1t);

    int attn_grid = BATCH * SPLIT * (NPIX / 64);   // 1024
    attn_kernel<<<attn_grid, 256, 0, stream>>>(f0t, f1t, lab1, partials);

    loss_kernel<<<(BATCH * NPIX) / 256, 256, 0, stream>>>(partials, lab0, out);
}